// Round 1
// baseline (124.585 us; speedup 1.0000x reference)
//
#include <hip/hip_runtime.h>
#include <hip/hip_bf16.h>
#include <math.h>

// Problem constants
#define BB 8
#define SS 2048
#define DD 256
#define FF 8
#define NTOK (BB*SS)   // 16384

// ---------------- Kernel A: h = tanh(x @ W1^T + b1) -> bf16 table ----------------
// Block: 256 threads. Tile: 64 tokens x 256 outputs. Thread tile: 8 tokens x 8 outputs.
#define MT 64
#define KB 32
#define STX 68    // xsT stride (MT + 4), *4B = 272 (16B-aligned)
#define STW 260   // wsT stride (DD + 4), *4B = 1040 (16B-aligned)

__device__ __forceinline__ unsigned short f2bf(float v) {
    unsigned u = __float_as_uint(v);
    unsigned r = u + 0x7FFFu + ((u >> 16) & 1u);   // round-to-nearest-even
    return (unsigned short)(r >> 16);
}

__global__ __launch_bounds__(256) void gemm_tanh_kernel(
    const float* __restrict__ x, const float* __restrict__ W1,
    const float* __restrict__ b1, unsigned short* __restrict__ table)
{
    __shared__ __align__(16) float xsT[KB][STX];   // k-major token tile
    __shared__ __align__(16) float wsT[KB][STW];   // k-major W1 tile

    const int tid  = threadIdx.x;
    const int tok0 = blockIdx.x * MT;

    // re-zero padding row 0 every launch (ws is poisoned before each call)
    if (blockIdx.x == 0) table[tid] = 0;   // 256 threads cover DD ushorts

    const int tg = tid >> 5;      // 0..7  -> tokens t0..t0+7
    const int jg = tid & 31;      // 0..31 -> outputs j0..j0+7
    const int t0 = tg * 8;
    const int j0 = jg * 8;

    float acc[8][8];
    #pragma unroll
    for (int a = 0; a < 8; ++a)
        #pragma unroll
        for (int b = 0; b < 8; ++b) acc[a][b] = 0.f;

    for (int k0 = 0; k0 < DD; k0 += KB) {
        __syncthreads();
        // stage x tile transposed: xsT[kk][t] = x[tok0+t][k0+kk]
        #pragma unroll
        for (int rep = 0; rep < (MT*KB)/256; ++rep) {
            int idx = rep * 256 + tid;
            int t  = idx >> 5;
            int kk = idx & 31;
            xsT[kk][t] = x[(size_t)(tok0 + t) * DD + k0 + kk];
        }
        // stage W1 tile transposed: wsT[kk][j] = W1[j][k0+kk]
        #pragma unroll
        for (int rep = 0; rep < (DD*KB)/256; ++rep) {
            int idx = rep * 256 + tid;
            int j  = idx >> 5;
            int kk = idx & 31;
            wsT[kk][j] = W1[(size_t)j * DD + k0 + kk];
        }
        __syncthreads();

        #pragma unroll 8
        for (int kk = 0; kk < KB; ++kk) {
            float4 xa = *(const float4*)&xsT[kk][t0];
            float4 xb = *(const float4*)&xsT[kk][t0 + 4];
            float4 wa = *(const float4*)&wsT[kk][j0];
            float4 wb = *(const float4*)&wsT[kk][j0 + 4];
            float xv[8] = {xa.x, xa.y, xa.z, xa.w, xb.x, xb.y, xb.z, xb.w};
            float wv[8] = {wa.x, wa.y, wa.z, wa.w, wb.x, wb.y, wb.z, wb.w};
            #pragma unroll
            for (int t = 0; t < 8; ++t)
                #pragma unroll
                for (int j = 0; j < 8; ++j)
                    acc[t][j] = fmaf(xv[t], wv[j], acc[t][j]);
        }
    }

    // epilogue: tanh(acc + b1) -> bf16 table rows [1 + token]
    float bj[8];
    #pragma unroll
    for (int j = 0; j < 8; ++j) bj[j] = b1[j0 + j];

    #pragma unroll
    for (int t = 0; t < 8; ++t) {
        ushort4 ua, ub;
        ua.x = f2bf(tanhf(acc[t][0] + bj[0]));
        ua.y = f2bf(tanhf(acc[t][1] + bj[1]));
        ua.z = f2bf(tanhf(acc[t][2] + bj[2]));
        ua.w = f2bf(tanhf(acc[t][3] + bj[3]));
        ub.x = f2bf(tanhf(acc[t][4] + bj[4]));
        ub.y = f2bf(tanhf(acc[t][5] + bj[5]));
        ub.z = f2bf(tanhf(acc[t][6] + bj[6]));
        ub.w = f2bf(tanhf(acc[t][7] + bj[7]));
        size_t row = (size_t)(1 + tok0 + t0 + t) * DD;
        *(ushort4*)&table[row + j0]     = ua;
        *(ushort4*)&table[row + j0 + 4] = ub;
    }
}

// ---------------- Kernel B: gather + max over F + dot(w2) + bias + mask ----------------
// One wave (64 lanes) per token; lane handles 4 contiguous dims via ushort4 loads.
__global__ __launch_bounds__(256) void gather_score_kernel(
    const unsigned short* __restrict__ table,
    const int* __restrict__ select_idx,
    const int* __restrict__ word_mask,
    const float* __restrict__ w2,
    const float* __restrict__ b2,
    float* __restrict__ out)
{
    const int tid  = threadIdx.x;
    const int lane = tid & 63;
    const int wv   = tid >> 6;
    const int i    = blockIdx.x * 4 + wv;     // token index
    const int d0   = lane * 4;

    const int* si = select_idx + (size_t)i * FF;

    float m0 = -INFINITY, m1 = -INFINITY, m2 = -INFINITY, m3 = -INFINITY;
    #pragma unroll
    for (int f = 0; f < FF; ++f) {
        int row = si[f];
        ushort4 u = *(const ushort4*)(table + (size_t)row * DD + d0);
        m0 = fmaxf(m0, __uint_as_float((unsigned)u.x << 16));
        m1 = fmaxf(m1, __uint_as_float((unsigned)u.y << 16));
        m2 = fmaxf(m2, __uint_as_float((unsigned)u.z << 16));
        m3 = fmaxf(m3, __uint_as_float((unsigned)u.w << 16));
    }

    float4 w4 = *(const float4*)(w2 + d0);
    float p = m0 * w4.x + m1 * w4.y + m2 * w4.z + m3 * w4.w;

    #pragma unroll
    for (int off = 32; off > 0; off >>= 1)
        p += __shfl_down(p, off, 64);

    if (lane == 0) {
        float neg = word_mask[i] ? 0.f : -10000.f;
        out[i] = p + b2[0] + neg;
    }
}

extern "C" void kernel_launch(void* const* d_in, const int* in_sizes, int n_in,
                              void* d_out, int out_size, void* d_ws, size_t ws_size,
                              hipStream_t stream) {
    const float* hs    = (const float*)d_in[0];   // [B,S,D] f32
    const int*   sidx  = (const int*)  d_in[1];   // [B,S,F] i32
    const int*   wmask = (const int*)  d_in[2];   // [B,S]   i32
    const float* W1    = (const float*)d_in[3];   // [D,D]   f32
    const float* b1    = (const float*)d_in[4];   // [D]     f32
    const float* w2    = (const float*)d_in[5];   // [D]     f32
    const float* b2    = (const float*)d_in[6];   // [1]     f32
    float* out = (float*)d_out;                   // [B,S]   f32

    unsigned short* table = (unsigned short*)d_ws;  // [1+NTOK, D] bf16 (~8.4 MB)

    gemm_tanh_kernel<<<NTOK / MT, 256, 0, stream>>>(hs, W1, b1, table);
    gather_score_kernel<<<NTOK / 4, 256, 0, stream>>>(table, sidx, wmask, w2, b2, out);
}

// Round 2
// 92.990 us; speedup vs baseline: 1.3398x; 1.3398x over previous
//
#include <hip/hip_runtime.h>
#include <hip/hip_bf16.h>
#include <math.h>

// Problem constants
#define BB 8
#define SS 2048
#define DD 256
#define FF 8
#define NTOK (BB*SS)   // 16384

typedef __bf16 bf16x8 __attribute__((ext_vector_type(8)));
typedef float  f32x4  __attribute__((ext_vector_type(4)));

// ---------------- Kernel A: h = tanh(x @ W1^T + b1) -> bf16 table via MFMA ----------------
// Block: 256 threads (4 waves). Tile: BM=64 tokens x BN=256 (all) outputs.
// K=256 in 8 steps of BK=32, double-buffered LDS, fp32->bf16 truncation at staging.
#define BM 64
#define BK 32
#define NSTEP (DD/BK)   // 8
#define XS 40           // LDS k-stride in ushorts: 80 B = 20 dwords -> conflict-free b128 reads, 16B aligned

__device__ __forceinline__ float fast_tanh(float x) {
    // tanh(x) = 1 - 2/(exp(2x)+1); saturates correctly at +-inf
    float e = __expf(2.0f * x);
    return 1.0f - 2.0f * __builtin_amdgcn_rcpf(e + 1.0f);
}

__device__ __forceinline__ unsigned pack2_bf16(float a, float b) {
    // truncation (error ~2^-8 rel; threshold is 199.7) -> 2 VALU per pair
    return (__float_as_uint(a) >> 16) | (__float_as_uint(b) & 0xFFFF0000u);
}

__global__ __launch_bounds__(256) void gemm_tanh_kernel(
    const float* __restrict__ x, const float* __restrict__ W1,
    const float* __restrict__ b1, unsigned short* __restrict__ table)
{
    __shared__ __align__(16) unsigned short xs[2][BM * XS];   // [m][k], k-contiguous
    __shared__ __align__(16) unsigned short wsb[2][DD * XS];  // [n][k], k-contiguous

    const int tid  = threadIdx.x;
    const int tok0 = blockIdx.x * BM;

    // re-zero padding row 0 (ws is re-poisoned before every launch)
    if (blockIdx.x == 0) table[tid] = 0;   // 256 threads cover the DD-ushort row

    const int wave = tid >> 6, lane = tid & 63;
    const int wm = wave >> 1;        // m-half: 32 rows
    const int wn = wave & 1;         // n-half: 128 cols
    const int lr = lane & 15;        // frag row/col within 16
    const int kg = lane >> 4;        // k-group (quad)

    f32x4 xr[2], wr[8];              // staging registers

    auto load_chunk = [&](int k0) {
        #pragma unroll
        for (int rep = 0; rep < 2; ++rep) {             // x: 64 rows x 8 kc slots
            int slot = rep * 256 + tid;
            int row = slot >> 3, kc = slot & 7;
            xr[rep] = *(const f32x4*)&x[(size_t)(tok0 + row) * DD + k0 + kc * 4];
        }
        #pragma unroll
        for (int rep = 0; rep < 8; ++rep) {             // W1: 256 rows x 8 kc slots
            int slot = rep * 256 + tid;
            int j = slot >> 3, kc = slot & 7;
            wr[rep] = *(const f32x4*)&W1[(size_t)j * DD + k0 + kc * 4];
        }
    };
    auto store_lds = [&](int buf) {
        #pragma unroll
        for (int rep = 0; rep < 2; ++rep) {
            int slot = rep * 256 + tid;
            int row = slot >> 3, kc = slot & 7;
            uint2 p;
            p.x = pack2_bf16(xr[rep].x, xr[rep].y);
            p.y = pack2_bf16(xr[rep].z, xr[rep].w);
            *(uint2*)&xs[buf][row * XS + kc * 4] = p;
        }
        #pragma unroll
        for (int rep = 0; rep < 8; ++rep) {
            int slot = rep * 256 + tid;
            int j = slot >> 3, kc = slot & 7;
            uint2 p;
            p.x = pack2_bf16(wr[rep].x, wr[rep].y);
            p.y = pack2_bf16(wr[rep].z, wr[rep].w);
            *(uint2*)&wsb[buf][j * XS + kc * 4] = p;
        }
    };

    f32x4 acc[2][8];
    #pragma unroll
    for (int mf = 0; mf < 2; ++mf)
        #pragma unroll
        for (int nf = 0; nf < 8; ++nf)
            acc[mf][nf] = (f32x4){0.f, 0.f, 0.f, 0.f};

    load_chunk(0);
    for (int s = 0; s < NSTEP; ++s) {
        const int buf = s & 1;
        store_lds(buf);
        __syncthreads();
        if (s + 1 < NSTEP) load_chunk((s + 1) * BK);    // overlap next global load with MFMA

        bf16x8 af[2], bfr[8];
        #pragma unroll
        for (int mf = 0; mf < 2; ++mf) {
            int m = wm * 32 + mf * 16 + lr;
            af[mf] = *(const bf16x8*)&xs[buf][m * XS + kg * 8];
        }
        #pragma unroll
        for (int nf = 0; nf < 8; ++nf) {
            int n = wn * 128 + nf * 16 + lr;
            bfr[nf] = *(const bf16x8*)&wsb[buf][n * XS + kg * 8];
        }
        #pragma unroll
        for (int mf = 0; mf < 2; ++mf)
            #pragma unroll
            for (int nf = 0; nf < 8; ++nf)
                acc[mf][nf] = __builtin_amdgcn_mfma_f32_16x16x32_bf16(
                    af[mf], bfr[nf], acc[mf][nf], 0, 0, 0);
        __syncthreads();
    }

    // epilogue: bias + tanh -> bf16 table. C/D layout: col=lane&15, row=(lane>>4)*4+reg
    float bj[8];
    #pragma unroll
    for (int nf = 0; nf < 8; ++nf) bj[nf] = b1[wn * 128 + nf * 16 + lr];

    #pragma unroll
    for (int mf = 0; mf < 2; ++mf) {
        #pragma unroll
        for (int r = 0; r < 4; ++r) {
            int m = tok0 + wm * 32 + mf * 16 + kg * 4 + r;
            size_t rowbase = (size_t)(1 + m) * DD;
            #pragma unroll
            for (int nf = 0; nf < 8; ++nf) {
                float v = fast_tanh(acc[mf][nf][r] + bj[nf]);
                table[rowbase + wn * 128 + nf * 16 + lr] =
                    (unsigned short)(__float_as_uint(v) >> 16);
            }
        }
    }
}

// ---------------- Kernel B: gather + max over F + dot(w2) + bias + mask ----------------
// One wave per token. Lanes split 32/32 over two f-rows; uint4 (16B) gathers.
__global__ __launch_bounds__(256) void gather_score_kernel(
    const unsigned short* __restrict__ table,
    const int* __restrict__ select_idx,
    const int* __restrict__ word_mask,
    const float* __restrict__ w2,
    const float* __restrict__ b2,
    float* __restrict__ out)
{
    const int tid  = threadIdx.x;
    const int lane = tid & 63;
    const int wv   = tid >> 6;
    const int i    = blockIdx.x * 4 + wv;    // token
    const int half = lane >> 5;              // which f of the pair
    const int c    = lane & 31;
    const int d0   = c * 8;                  // 8 dims (16 B) per lane

    const int* si = select_idx + (size_t)i * FF;
    int rows[4];
    #pragma unroll
    for (int it = 0; it < 4; ++it) rows[it] = si[2 * it + half];

    float m[8];
    #pragma unroll
    for (int j = 0; j < 8; ++j) m[j] = -INFINITY;

    #pragma unroll
    for (int it = 0; it < 4; ++it) {
        uint4 u = *(const uint4*)(table + (size_t)rows[it] * DD + d0);
        m[0] = fmaxf(m[0], __uint_as_float(u.x << 16));
        m[1] = fmaxf(m[1], __uint_as_float(u.x & 0xFFFF0000u));
        m[2] = fmaxf(m[2], __uint_as_float(u.y << 16));
        m[3] = fmaxf(m[3], __uint_as_float(u.y & 0xFFFF0000u));
        m[4] = fmaxf(m[4], __uint_as_float(u.z << 16));
        m[5] = fmaxf(m[5], __uint_as_float(u.z & 0xFFFF0000u));
        m[6] = fmaxf(m[6], __uint_as_float(u.w << 16));
        m[7] = fmaxf(m[7], __uint_as_float(u.w & 0xFFFF0000u));
    }

    // elementwise max across the two half-waves (before the dot — w2 may be negative)
    #pragma unroll
    for (int j = 0; j < 8; ++j) m[j] = fmaxf(m[j], __shfl_xor(m[j], 32));

    f32x4 wa = *(const f32x4*)&w2[d0];
    f32x4 wb = *(const f32x4*)&w2[d0 + 4];
    float p = m[0] * wa.x + m[1] * wa.y + m[2] * wa.z + m[3] * wa.w
            + m[4] * wb.x + m[5] * wb.y + m[6] * wb.z + m[7] * wb.w;

    #pragma unroll
    for (int off = 16; off; off >>= 1) p += __shfl_xor(p, off);

    if (lane == 0) {
        float neg = word_mask[i] ? 0.f : -10000.f;
        out[i] = p + b2[0] + neg;
    }
}

extern "C" void kernel_launch(void* const* d_in, const int* in_sizes, int n_in,
                              void* d_out, int out_size, void* d_ws, size_t ws_size,
                              hipStream_t stream) {
    const float* hs    = (const float*)d_in[0];   // [B,S,D] f32
    const int*   sidx  = (const int*)  d_in[1];   // [B,S,F] i32
    const int*   wmask = (const int*)  d_in[2];   // [B,S]   i32
    const float* W1    = (const float*)d_in[3];   // [D,D]   f32
    const float* b1    = (const float*)d_in[4];   // [D]     f32
    const float* w2    = (const float*)d_in[5];   // [D]     f32
    const float* b2    = (const float*)d_in[6];   // [1]     f32
    float* out = (float*)d_out;                   // [B,S]   f32

    unsigned short* table = (unsigned short*)d_ws;  // [1+NTOK, D] bf16 (~8.4 MB)

    gemm_tanh_kernel<<<NTOK / BM, 256, 0, stream>>>(hs, W1, b1, table);
    gather_score_kernel<<<NTOK / 4, 256, 0, stream>>>(table, sidx, wmask, w2, b2, out);
}

// Round 3
// 91.899 us; speedup vs baseline: 1.3557x; 1.0119x over previous
//
#include <hip/hip_runtime.h>
#include <hip/hip_bf16.h>
#include <math.h>

// Problem constants
#define BB 8
#define SS 2048
#define DD 256
#define FF 8
#define NTOK (BB*SS)   // 16384

typedef __bf16 bf16x8 __attribute__((ext_vector_type(8)));
typedef float  f32x4  __attribute__((ext_vector_type(4)));
typedef float  f32x2  __attribute__((ext_vector_type(2)));

// ---------------- Kernel A: h = tanh(x @ W1^T + b1) -> fp8(e4m3) table via MFMA ----------
// Tile: BM=128 tokens x BN=64 outputs, 512 threads (8 waves), grid = 128*4 = 512 blocks
// -> 2 blocks/CU co-resident, 4 waves/SIMD. K=256 in 8 steps of BK=32, double-buffered LDS.
#define BM 128
#define BN 64
#define BK 32
#define NSTEP (DD/BK)   // 8
#define XS 40           // LDS k-stride in ushorts (80 B = 20 dwords): <=2-way conflicts on b128

__device__ __forceinline__ float fast_tanh(float x) {
    float e = __expf(2.0f * x);
    return 1.0f - 2.0f * __builtin_amdgcn_rcpf(e + 1.0f);
}

__device__ __forceinline__ unsigned pack2_bf16(float a, float b) {
    return (__float_as_uint(a) >> 16) | (__float_as_uint(b) & 0xFFFF0000u);
}

__device__ __forceinline__ unsigned char f32_to_fp8(float v) {
    // HW OCP e4m3 convert (gfx950): byte0 of the packed result
    return (unsigned char)(__builtin_amdgcn_cvt_pk_fp8_f32(v, v, 0, false) & 0xFF);
}

__global__ __launch_bounds__(512, 4) void gemm_tanh_kernel(
    const float* __restrict__ x, const float* __restrict__ W1,
    const float* __restrict__ b1, unsigned char* __restrict__ table)
{
    __shared__ __align__(16) unsigned short xs[2][BM * XS];   // 20 KB
    __shared__ __align__(16) unsigned short wsb[2][BN * XS];  // 10 KB

    const int tid  = threadIdx.x;
    const int bx   = blockIdx.x;
    const int tok0 = (bx >> 2) * BM;
    const int n0   = (bx & 3) * BN;

    // re-zero padding row 0 (256 fp8 bytes); ws is re-poisoned before every launch
    if (bx == 0 && tid < 64) ((unsigned int*)table)[tid] = 0u;

    const int wave = tid >> 6, lane = tid & 63;
    const int wm = wave >> 1;        // 0..3: 32-row m band
    const int wn = wave & 1;         // 0..1: 32-col n band
    const int lr = lane & 15;
    const int kg = lane >> 4;

    f32x4 xr[2], wr;                 // staging registers

    auto load_chunk = [&](int k0) {
        #pragma unroll
        for (int rep = 0; rep < 2; ++rep) {            // x: 128 rows x 8 kc slots = 1024
            int slot = rep * 512 + tid;
            int row = slot >> 3, kc = slot & 7;
            xr[rep] = *(const f32x4*)&x[(size_t)(tok0 + row) * DD + k0 + kc * 4];
        }
        {                                               // W1 slice: 64 rows x 8 kc = 512
            int row = tid >> 3, kc = tid & 7;
            wr = *(const f32x4*)&W1[(size_t)(n0 + row) * DD + k0 + kc * 4];
        }
    };
    auto store_lds = [&](int buf) {
        #pragma unroll
        for (int rep = 0; rep < 2; ++rep) {
            int slot = rep * 512 + tid;
            int row = slot >> 3, kc = slot & 7;
            uint2 p;
            p.x = pack2_bf16(xr[rep].x, xr[rep].y);
            p.y = pack2_bf16(xr[rep].z, xr[rep].w);
            *(uint2*)&xs[buf][row * XS + kc * 4] = p;
        }
        {
            int row = tid >> 3, kc = tid & 7;
            uint2 p;
            p.x = pack2_bf16(wr.x, wr.y);
            p.y = pack2_bf16(wr.z, wr.w);
            *(uint2*)&wsb[buf][row * XS + kc * 4] = p;
        }
    };

    f32x4 acc[2][2];
    #pragma unroll
    for (int mf = 0; mf < 2; ++mf)
        #pragma unroll
        for (int nf = 0; nf < 2; ++nf)
            acc[mf][nf] = (f32x4){0.f, 0.f, 0.f, 0.f};

    load_chunk(0);
    for (int s = 0; s < NSTEP; ++s) {
        const int buf = s & 1;
        store_lds(buf);
        __syncthreads();
        if (s + 1 < NSTEP) load_chunk((s + 1) * BK);   // prefetch overlaps MFMA phase

        bf16x8 af[2], bfr[2];
        #pragma unroll
        for (int mf = 0; mf < 2; ++mf) {
            int m = wm * 32 + mf * 16 + lr;
            af[mf] = *(const bf16x8*)&xs[buf][m * XS + kg * 8];
        }
        #pragma unroll
        for (int nf = 0; nf < 2; ++nf) {
            int n = wn * 32 + nf * 16 + lr;
            bfr[nf] = *(const bf16x8*)&wsb[buf][n * XS + kg * 8];
        }
        #pragma unroll
        for (int mf = 0; mf < 2; ++mf)
            #pragma unroll
            for (int nf = 0; nf < 2; ++nf)
                acc[mf][nf] = __builtin_amdgcn_mfma_f32_16x16x32_bf16(
                    af[mf], bfr[nf], acc[mf][nf], 0, 0, 0);
        __syncthreads();
    }

    // epilogue: bias + tanh -> fp8 table. C/D layout: col=lane&15, row=(lane>>4)*4+reg
    float bj[2];
    #pragma unroll
    for (int nf = 0; nf < 2; ++nf) bj[nf] = b1[n0 + wn * 32 + nf * 16 + lr];

    #pragma unroll
    for (int mf = 0; mf < 2; ++mf) {
        #pragma unroll
        for (int r = 0; r < 4; ++r) {
            int m = tok0 + wm * 32 + mf * 16 + kg * 4 + r;
            size_t rowbase = (size_t)(1 + m) * DD;
            #pragma unroll
            for (int nf = 0; nf < 2; ++nf) {
                float v = fast_tanh(acc[mf][nf][r] + bj[nf]);
                table[rowbase + n0 + wn * 32 + nf * 16 + lr] = f32_to_fp8(v);
            }
        }
    }
}

// ---------------- Kernel B: fp8 gather + max over F + dot(w2) + bias + mask ----------------
// One wave per token. Halves of the wave take alternating f-rows; uint2 (8 fp8) per lane.
__global__ __launch_bounds__(256) void gather_score_kernel(
    const unsigned char* __restrict__ table,
    const int* __restrict__ select_idx,
    const int* __restrict__ word_mask,
    const float* __restrict__ w2,
    const float* __restrict__ b2,
    float* __restrict__ out)
{
    const int tid  = threadIdx.x;
    const int lane = tid & 63;
    const int wv   = tid >> 6;
    const int i    = blockIdx.x * 4 + wv;    // token
    const int half = lane >> 5;
    const int c    = lane & 31;
    const int d0   = c * 8;                  // 8 dims (8 B) per lane

    // wave-uniform index loads (scalarizable), per-lane select by half
    const int4* sp = (const int4*)(select_idx + (size_t)i * FF);
    int4 q0 = sp[0], q1 = sp[1];
    int rows[4];
    rows[0] = half ? q0.y : q0.x;
    rows[1] = half ? q0.w : q0.z;
    rows[2] = half ? q1.y : q1.x;
    rows[3] = half ? q1.w : q1.z;

    float m[8];
    #pragma unroll
    for (int j = 0; j < 8; ++j) m[j] = -INFINITY;

    #pragma unroll
    for (int it = 0; it < 4; ++it) {
        uint2 u = *(const uint2*)(table + (size_t)rows[it] * DD + d0);
        f32x2 a0 = __builtin_amdgcn_cvt_pk_f32_fp8(u.x, false);
        f32x2 a1 = __builtin_amdgcn_cvt_pk_f32_fp8(u.x, true);
        f32x2 a2 = __builtin_amdgcn_cvt_pk_f32_fp8(u.y, false);
        f32x2 a3 = __builtin_amdgcn_cvt_pk_f32_fp8(u.y, true);
        m[0] = fmaxf(m[0], a0.x); m[1] = fmaxf(m[1], a0.y);
        m[2] = fmaxf(m[2], a1.x); m[3] = fmaxf(m[3], a1.y);
        m[4] = fmaxf(m[4], a2.x); m[5] = fmaxf(m[5], a2.y);
        m[6] = fmaxf(m[6], a3.x); m[7] = fmaxf(m[7], a3.y);
    }

    // elementwise max across the two half-waves (must precede the dot)
    #pragma unroll
    for (int j = 0; j < 8; ++j) m[j] = fmaxf(m[j], __shfl_xor(m[j], 32));

    f32x4 wa = *(const f32x4*)&w2[d0];
    f32x4 wb = *(const f32x4*)&w2[d0 + 4];
    float p = m[0] * wa.x + m[1] * wa.y + m[2] * wa.z + m[3] * wa.w
            + m[4] * wb.x + m[5] * wb.y + m[6] * wb.z + m[7] * wb.w;

    #pragma unroll
    for (int off = 16; off; off >>= 1) p += __shfl_xor(p, off);

    if (lane == 0) {
        float neg = word_mask[i] ? 0.f : -10000.f;
        out[i] = p + b2[0] + neg;
    }
}

extern "C" void kernel_launch(void* const* d_in, const int* in_sizes, int n_in,
                              void* d_out, int out_size, void* d_ws, size_t ws_size,
                              hipStream_t stream) {
    const float* hs    = (const float*)d_in[0];   // [B,S,D] f32
    const int*   sidx  = (const int*)  d_in[1];   // [B,S,F] i32
    const int*   wmask = (const int*)  d_in[2];   // [B,S]   i32
    const float* W1    = (const float*)d_in[3];   // [D,D]   f32
    const float* b1    = (const float*)d_in[4];   // [D]     f32
    const float* w2    = (const float*)d_in[5];   // [D]     f32
    const float* b2    = (const float*)d_in[6];   // [1]     f32
    float* out = (float*)d_out;                   // [B,S]   f32

    unsigned char* table = (unsigned char*)d_ws;  // [1+NTOK, D] fp8 e4m3 (~4.2 MB)

    gemm_tanh_kernel<<<(NTOK / BM) * (DD / BN), 512, 0, stream>>>(hs, W1, b1, table);
    gather_score_kernel<<<NTOK / 4, 256, 0, stream>>>(table, sidx, wmask, w2, b2, out);
}

// Round 4
// 85.820 us; speedup vs baseline: 1.4517x; 1.0708x over previous
//
#include <hip/hip_runtime.h>
#include <hip/hip_bf16.h>
#include <math.h>

// Problem constants
#define BB 8
#define SS 2048
#define DD 256
#define FF 8
#define NTOK (BB*SS)   // 16384

typedef __bf16 bf16x8 __attribute__((ext_vector_type(8)));
typedef float  f32x4  __attribute__((ext_vector_type(4)));
typedef float  f32x2  __attribute__((ext_vector_type(2)));

// ---------------- Kernel A: h = tanh(x @ W1^T + b1) -> fp8(e4m3) table via MFMA ----------
// Tile: BM=128 tokens x BN=64 outputs, 512 threads (8 waves), grid 512 = 2 blocks/CU.
// K=256 in 4 steps of BK=64, double-buffered LDS, ONE barrier per step.
// XCD swizzle: the 4 n-blocks of a token group share an XCD -> x refetch is L2-local.
#define BM 128
#define BN 64
#define BK 64
#define NSTEP (DD/BK)   // 4
#define XS 72           // LDS row stride in ushorts (BK + 8 pad): 144 B, 16B-aligned

__device__ __forceinline__ float fast_tanh(float x) {
    float e = __expf(2.0f * x);
    return 1.0f - 2.0f * __builtin_amdgcn_rcpf(e + 1.0f);
}

__device__ __forceinline__ unsigned pack2_bf16(float a, float b) {
    return (__float_as_uint(a) >> 16) | (__float_as_uint(b) & 0xFFFF0000u);
}

__device__ __forceinline__ unsigned char f32_to_fp8(float v) {
    return (unsigned char)(__builtin_amdgcn_cvt_pk_fp8_f32(v, v, 0, false) & 0xFF);
}

__global__ __launch_bounds__(512, 4) void gemm_tanh_kernel(
    const float* __restrict__ x, const float* __restrict__ W1,
    const float* __restrict__ b1, unsigned char* __restrict__ table)
{
    __shared__ __align__(16) unsigned short xs[2][BM * XS];   // 36 KB (reused as fp8 scratch)
    __shared__ __align__(16) unsigned short wsb[2][BN * XS];  // 18 KB

    const int tid  = threadIdx.x;
    const int bx   = blockIdx.x;
    const int tokgrp = bx & 127;          // same-XCD for the 4 n-blocks of a token group
    const int nblk   = bx >> 7;
    const int tok0 = tokgrp * BM;
    const int n0   = nblk * BN;

    // re-zero padding row 0 (256 fp8 bytes); ws is re-poisoned before every launch
    if (bx == 0 && tid < 64) ((unsigned int*)table)[tid] = 0u;

    const int wave = tid >> 6, lane = tid & 63;
    const int wm = wave >> 1;        // 0..3: 32-row m band
    const int wn = wave & 1;         // 0..1: 32-col n band
    const int lr = lane & 15;
    const int kg = lane >> 4;

    f32x4 xr[4], wr[2];              // staging registers

    auto load_chunk = [&](int k0) {
        #pragma unroll
        for (int rep = 0; rep < 4; ++rep) {            // x: 128 rows x 16 f32x4 = 2048 slots
            int slot = rep * 512 + tid;
            int row = slot >> 4, kc = slot & 15;
            xr[rep] = *(const f32x4*)&x[(size_t)(tok0 + row) * DD + k0 + kc * 4];
        }
        #pragma unroll
        for (int rep = 0; rep < 2; ++rep) {            // W1: 64 rows x 16 f32x4 = 1024 slots
            int slot = rep * 512 + tid;
            int row = slot >> 4, kc = slot & 15;
            wr[rep] = *(const f32x4*)&W1[(size_t)(n0 + row) * DD + k0 + kc * 4];
        }
    };
    auto store_lds = [&](int buf) {
        #pragma unroll
        for (int rep = 0; rep < 4; ++rep) {
            int slot = rep * 512 + tid;
            int row = slot >> 4, kc = slot & 15;
            uint2 p;
            p.x = pack2_bf16(xr[rep].x, xr[rep].y);
            p.y = pack2_bf16(xr[rep].z, xr[rep].w);
            *(uint2*)&xs[buf][row * XS + kc * 4] = p;
        }
        #pragma unroll
        for (int rep = 0; rep < 2; ++rep) {
            int slot = rep * 512 + tid;
            int row = slot >> 4, kc = slot & 15;
            uint2 p;
            p.x = pack2_bf16(wr[rep].x, wr[rep].y);
            p.y = pack2_bf16(wr[rep].z, wr[rep].w);
            *(uint2*)&wsb[buf][row * XS + kc * 4] = p;
        }
    };

    f32x4 acc[2][2];
    #pragma unroll
    for (int mf = 0; mf < 2; ++mf)
        #pragma unroll
        for (int nf = 0; nf < 2; ++nf)
            acc[mf][nf] = (f32x4){0.f, 0.f, 0.f, 0.f};

    load_chunk(0);
    store_lds(0);

    for (int s = 0; s < NSTEP; ++s) {
        __syncthreads();                               // one barrier per step
        const int buf = s & 1;
        if (s + 1 < NSTEP) load_chunk((s + 1) * BK);   // global loads in flight early

        bf16x8 af[2][2], bfr[2][2];                    // [k-chunk][frag]
        #pragma unroll
        for (int c = 0; c < 2; ++c) {
            #pragma unroll
            for (int mf = 0; mf < 2; ++mf) {
                int m = wm * 32 + mf * 16 + lr;
                af[c][mf] = *(const bf16x8*)&xs[buf][m * XS + c * 32 + kg * 8];
            }
            #pragma unroll
            for (int nf = 0; nf < 2; ++nf) {
                int n = wn * 32 + nf * 16 + lr;
                bfr[c][nf] = *(const bf16x8*)&wsb[buf][n * XS + c * 32 + kg * 8];
            }
        }
        if (s + 1 < NSTEP) store_lds(buf ^ 1);         // buf^1 reads drained at this step's barrier

        #pragma unroll
        for (int c = 0; c < 2; ++c)
            #pragma unroll
            for (int mf = 0; mf < 2; ++mf)
                #pragma unroll
                for (int nf = 0; nf < 2; ++nf)
                    acc[mf][nf] = __builtin_amdgcn_mfma_f32_16x16x32_bf16(
                        af[c][mf], bfr[c][nf], acc[mf][nf], 0, 0, 0);
    }

    // ---- epilogue: bias + tanh -> fp8, LDS transpose, coalesced uint4 stores ----
    float bj[2];
    #pragma unroll
    for (int nf = 0; nf < 2; ++nf) bj[nf] = b1[n0 + wn * 32 + nf * 16 + lr];

    __syncthreads();                                   // safe to reuse xs as scratch
    unsigned char* sc = (unsigned char*)&xs[0][0];     // [BM][80] fp8 scratch (10 KB)
    #pragma unroll
    for (int mf = 0; mf < 2; ++mf) {
        #pragma unroll
        for (int r = 0; r < 4; ++r) {
            int m = wm * 32 + mf * 16 + kg * 4 + r;    // C/D layout: col=lane&15, row=kg*4+reg
            #pragma unroll
            for (int nf = 0; nf < 2; ++nf) {
                float v = fast_tanh(acc[mf][nf][r] + bj[nf]);
                sc[m * 80 + wn * 32 + nf * 16 + lr] = f32_to_fp8(v);
            }
        }
    }
    __syncthreads();
    {
        int row = tid >> 2;                            // 128 rows x 64 B, 16 B per thread
        int off = (tid & 3) * 16;
        uint4 v = *(const uint4*)&sc[row * 80 + off];
        *(uint4*)&table[(size_t)(1 + tok0 + row) * DD + n0 + off] = v;
    }
}

// ---------------- Kernel B: fp8 gather + max over F + dot(w2) + bias + mask ----------------
// One wave per token. Halves of the wave take alternating f-rows; uint2 (8 fp8) per lane.
__global__ __launch_bounds__(256) void gather_score_kernel(
    const unsigned char* __restrict__ table,
    const int* __restrict__ select_idx,
    const int* __restrict__ word_mask,
    const float* __restrict__ w2,
    const float* __restrict__ b2,
    float* __restrict__ out)
{
    const int tid  = threadIdx.x;
    const int lane = tid & 63;
    const int wv   = tid >> 6;
    const int i    = blockIdx.x * 4 + wv;    // token
    const int half = lane >> 5;
    const int c    = lane & 31;
    const int d0   = c * 8;                  // 8 dims (8 B) per lane

    const int4* sp = (const int4*)(select_idx + (size_t)i * FF);
    int4 q0 = sp[0], q1 = sp[1];
    int rows[4];
    rows[0] = half ? q0.y : q0.x;
    rows[1] = half ? q0.w : q0.z;
    rows[2] = half ? q1.y : q1.x;
    rows[3] = half ? q1.w : q1.z;

    float m[8];
    #pragma unroll
    for (int j = 0; j < 8; ++j) m[j] = -INFINITY;

    #pragma unroll
    for (int it = 0; it < 4; ++it) {
        uint2 u = *(const uint2*)(table + (size_t)rows[it] * DD + d0);
        f32x2 a0 = __builtin_amdgcn_cvt_pk_f32_fp8(u.x, false);
        f32x2 a1 = __builtin_amdgcn_cvt_pk_f32_fp8(u.x, true);
        f32x2 a2 = __builtin_amdgcn_cvt_pk_f32_fp8(u.y, false);
        f32x2 a3 = __builtin_amdgcn_cvt_pk_f32_fp8(u.y, true);
        m[0] = fmaxf(m[0], a0.x); m[1] = fmaxf(m[1], a0.y);
        m[2] = fmaxf(m[2], a1.x); m[3] = fmaxf(m[3], a1.y);
        m[4] = fmaxf(m[4], a2.x); m[5] = fmaxf(m[5], a2.y);
        m[6] = fmaxf(m[6], a3.x); m[7] = fmaxf(m[7], a3.y);
    }

    #pragma unroll
    for (int j = 0; j < 8; ++j) m[j] = fmaxf(m[j], __shfl_xor(m[j], 32));

    f32x4 wa = *(const f32x4*)&w2[d0];
    f32x4 wb = *(const f32x4*)&w2[d0 + 4];
    float p = m[0] * wa.x + m[1] * wa.y + m[2] * wa.z + m[3] * wa.w
            + m[4] * wb.x + m[5] * wb.y + m[6] * wb.z + m[7] * wb.w;

    #pragma unroll
    for (int off = 16; off; off >>= 1) p += __shfl_xor(p, off);

    if (lane == 0) {
        float neg = word_mask[i] ? 0.f : -10000.f;
        out[i] = p + b2[0] + neg;
    }
}

extern "C" void kernel_launch(void* const* d_in, const int* in_sizes, int n_in,
                              void* d_out, int out_size, void* d_ws, size_t ws_size,
                              hipStream_t stream) {
    const float* hs    = (const float*)d_in[0];   // [B,S,D] f32
    const int*   sidx  = (const int*)  d_in[1];   // [B,S,F] i32
    const int*   wmask = (const int*)  d_in[2];   // [B,S]   i32
    const float* W1    = (const float*)d_in[3];   // [D,D]   f32
    const float* b1    = (const float*)d_in[4];   // [D]     f32
    const float* w2    = (const float*)d_in[5];   // [D]     f32
    const float* b2    = (const float*)d_in[6];   // [1]     f32
    float* out = (float*)d_out;                   // [B,S]   f32

    unsigned char* table = (unsigned char*)d_ws;  // [1+NTOK, D] fp8 e4m3 (~4.2 MB)

    gemm_tanh_kernel<<<(NTOK / BM) * (DD / BN), 512, 0, stream>>>(hs, W1, b1, table);
    gather_score_kernel<<<NTOK / 4, 256, 0, stream>>>(table, sidx, wmask, w2, b2, out);
}